// Round 3
// baseline (153.625 us; speedup 1.0000x reference)
//
#include <hip/hip_runtime.h>
#include <stdint.h>

// ContrastiveLoss: mean over all pairs of (same-label ? d2 : relu(1-dist)^2)
// z: [8192,128] fp32, labels: [8192] int32. Output: 1 fp32 scalar.
//
// R12: SLOPE PROBE. R11 removed a whole dispatch and dur_us moved +0.004us
// -> timed quantity is constant-dominated; our kernels are invisible in
// top-5 (all 42us harness poison fills). This round repeats the persistent
// tile loop NREP=8x (result rescaled by 1/8, exact) to (a) measure
// d(dur_us)/d(T_loss) and (b) push loss_kernel to top-1 so its counters
// (MfmaUtil/VALUBusy/FETCH/conflicts) become visible for the first time.
// Expected dur_us ~= 73 + 7*T_loss. If unchanged at ~73 -> harness floor,
// declare roofline with evidence.
// Core is byte-identical to the verified R9/R11 core (73.0us, absmax 0).

#define NROWS 8192
#define DIMK  128
#define NB    64                     // 8192 / 128
#define NTILE (NB * (NB + 1) / 2)    // 2080 upper-triangle tiles
#define NPERS 512                    // persistent blocks (2 per CU)
#define NREP  8                      // slope-probe repeat factor

typedef __attribute__((ext_vector_type(4))) float f32x4;

#define AS_GLOBAL __attribute__((address_space(1)))
#define AS_LDS    __attribute__((address_space(3)))

// Convert z -> fp8 e4m3 with granule-swizzled rows: logical k lives in
// granule g = ((k>>3)&3)<<2 | (k>>5), stored at byte ((g^(row&15))<<3)+(k&7).
// Dot-invariant. Also per-row sum of squares of ROUNDED values (diag d2==0).
__global__ __launch_bounds__(256) void prep_kernel(
    const float* __restrict__ z, unsigned char* __restrict__ zb,
    float* __restrict__ sq) {
  int tid = threadIdx.x;
  int row = (blockIdx.x << 3) + (tid >> 5);          // 8 rows per block
  int c32 = tid & 31;                                // 32 lanes per row
  float4 x = ((const float4*)(z + (size_t)row * DIMK))[c32];
  int u = __builtin_amdgcn_cvt_pk_fp8_f32(x.x, x.y, 0, false);
  u     = __builtin_amdgcn_cvt_pk_fp8_f32(x.z, x.w, u, true);
  float r0 = __builtin_amdgcn_cvt_f32_fp8(u, 0);
  float r1 = __builtin_amdgcn_cvt_f32_fp8(u, 1);
  float r2 = __builtin_amdgcn_cvt_f32_fp8(u, 2);
  float r3 = __builtin_amdgcn_cvt_f32_fp8(u, 3);
  float s = (r0 * r0 + r1 * r1) + (r2 * r2 + r3 * r3);
  int k0 = c32 << 2;                                 // logical k of byte 0
  int g  = (((k0 >> 3) & 3) << 2) | (k0 >> 5);       // granule index
  int p  = ((g ^ (row & 15)) << 3) + (k0 & 7);       // 4B-aligned
  *(uint32_t*)(zb + (size_t)row * DIMK + p) = (uint32_t)u;
  #pragma unroll
  for (int off = 16; off; off >>= 1) s += __shfl_down(s, off, 32);
  if (c32 == 0) sq[row] = s;
}

__device__ __forceinline__ void decode_tile(int t, int& bi, int& bj) {
  #define TRI(rr) ((rr) * NB - ((rr) * ((rr) - 1)) / 2)
  int r = (int)(((float)(2 * NB + 1) -
                 sqrtf((float)((2 * NB + 1) * (2 * NB + 1) - 8 * t))) * 0.5f);
  if (r < 0) r = 0; if (r > NB - 1) r = NB - 1;
  while (TRI(r + 1) <= t) ++r;
  while (TRI(r) > t) --r;
  bi = r; bj = t - TRI(r) + r;
}

// Persistent: 512 blocks x 512 thr (8 waves, 4x2); block b computes tiles
// b, b+512, ... with double-buffered staging, repeated NREP times (probe).
__global__ __launch_bounds__(512, 4) void loss_kernel(
    const unsigned char* __restrict__ zb, const float* __restrict__ sq,
    const int* __restrict__ labels, float* __restrict__ out) {
  __shared__ __align__(16) unsigned char buf[2][32768];   // [A 16K | B 16K]
  __shared__ __align__(16) unsigned char sqlab[2][2048];  // [sqA|laA|sqB|laB]
  __shared__ float red[8];

  int tid = threadIdx.x, lane = tid & 63, wave = tid >> 6;
  int wm = wave >> 1, wn = wave & 1;
  int lc = lane & 15;                                // frag row (A)/col (out)
  int q  = lane >> 4;                                // quad: k-granule select

  // sq/label staging role for this wave (one masked DMA per tile):
  //   w0,w1->sqA halves; w2,w3->laA; w4,w5->sqB; w6,w7->laB
  int sl_isB  = wave >> 2;
  int sl_isLa = (wave >> 1) & 1;
  int sl_half = wave & 1;

  float psum_acc = 0.f;

  #pragma unroll 1
  for (int rep = 0; rep < NREP; ++rep) {
    __syncthreads();   // all waves done reading LDS from previous rep

    int b = blockIdx.x;
    int bi, bj;
    decode_tile(b, bi, bj);

    // ---- prologue: stage tile b into buffer 0 ----
    {
      const unsigned char* Ab = zb + (((size_t)bi << 7) * DIMK);
      const unsigned char* Bb = zb + (((size_t)bj << 7) * DIMK);
      #pragma unroll
      for (int it = 0; it < 2; ++it) {
        int L0 = (it << 9) + (wave << 6);
        __builtin_amdgcn_global_load_lds(
            (const AS_GLOBAL void*)(uintptr_t)(Ab + (size_t)(L0 + lane) * 16),
            (AS_LDS void*)(uintptr_t)(&buf[0][(size_t)L0 * 16]), 16, 0, 0);
        __builtin_amdgcn_global_load_lds(
            (const AS_GLOBAL void*)(uintptr_t)(Bb + (size_t)(L0 + lane) * 16),
            (AS_LDS void*)(uintptr_t)(&buf[0][16384 + (size_t)L0 * 16]), 16, 0, 0);
      }
      const char* p0 = sl_isLa ? (const char*)labels : (const char*)sq;
      const char* src = p0 + ((size_t)((sl_isB ? bj : bi) << 7) << 2)
                           + (sl_half << 8);
      if (lane < 16)
        __builtin_amdgcn_global_load_lds(
            (const AS_GLOBAL void*)(uintptr_t)(src + lane * 16),
            (AS_LDS void*)(uintptr_t)(&sqlab[0][wave << 8]), 16, 0, 0);
    }

    int cur = 0;
    for (int t = b; ; t += NPERS) {
      int tn = t + NPERS;
      bool hasNext = tn < NTILE;

      // ---- wait for current tile's DMA (issued a full iteration ago) ----
      asm volatile("s_waitcnt vmcnt(0)" ::: "memory");
      __syncthreads();   // implicit drain is free: vmcnt already 0

      // ---- prefetch next tile into the other buffer ----
      int bin = bi, bjn = bj;
      if (hasNext) {
        decode_tile(tn, bin, bjn);
        int nc = cur ^ 1;
        const unsigned char* Ab = zb + (((size_t)bin << 7) * DIMK);
        const unsigned char* Bb = zb + (((size_t)bjn << 7) * DIMK);
        #pragma unroll
        for (int it = 0; it < 2; ++it) {
          int L0 = (it << 9) + (wave << 6);
          __builtin_amdgcn_global_load_lds(
              (const AS_GLOBAL void*)(uintptr_t)(Ab + (size_t)(L0 + lane) * 16),
              (AS_LDS void*)(uintptr_t)(&buf[nc][(size_t)L0 * 16]), 16, 0, 0);
          __builtin_amdgcn_global_load_lds(
              (const AS_GLOBAL void*)(uintptr_t)(Bb + (size_t)(L0 + lane) * 16),
              (AS_LDS void*)(uintptr_t)(&buf[nc][16384 + (size_t)L0 * 16]), 16, 0, 0);
        }
        const char* p0 = sl_isLa ? (const char*)labels : (const char*)sq;
        const char* src = p0 + ((size_t)((sl_isB ? bjn : bin) << 7) << 2)
                             + (sl_half << 8);
        if (lane < 16)
          __builtin_amdgcn_global_load_lds(
              (const AS_GLOBAL void*)(uintptr_t)(src + lane * 16),
              (AS_LDS void*)(uintptr_t)(&sqlab[nc][wave << 8]), 16, 0, 0);
      }

      // ---- compute tile t from buf[cur] ----
      const unsigned char* ldsA = &buf[cur][0];
      const unsigned char* ldsB = &buf[cur][16384];
      const float* sqAl = (const float*)&sqlab[cur][0];
      const int*   laAl = (const int*)&sqlab[cur][512];
      const float* sqBl = (const float*)&sqlab[cur][1024];
      const int*   laBl = (const int*)&sqlab[cur][1536];

      f32x4 acc[2][4] = {};
      #pragma unroll
      for (int ks = 0; ks < 4; ++ks) {
        int so = ((((q << 2) | ks) ^ lc) << 3);        // swizzled slot offset
        long a0 = *(const long*)(ldsA + ((wm << 5)      + lc) * 128 + so);
        long a1 = *(const long*)(ldsA + ((wm << 5) + 16 + lc) * 128 + so);
        long b0 = *(const long*)(ldsB + ((wn << 6)      + lc) * 128 + so);
        long b1 = *(const long*)(ldsB + ((wn << 6) + 16 + lc) * 128 + so);
        long b2 = *(const long*)(ldsB + ((wn << 6) + 32 + lc) * 128 + so);
        long b3 = *(const long*)(ldsB + ((wn << 6) + 48 + lc) * 128 + so);
        acc[0][0] = __builtin_amdgcn_mfma_f32_16x16x32_fp8_fp8(a0, b0, acc[0][0], 0, 0, 0);
        acc[0][1] = __builtin_amdgcn_mfma_f32_16x16x32_fp8_fp8(a0, b1, acc[0][1], 0, 0, 0);
        acc[0][2] = __builtin_amdgcn_mfma_f32_16x16x32_fp8_fp8(a0, b2, acc[0][2], 0, 0, 0);
        acc[0][3] = __builtin_amdgcn_mfma_f32_16x16x32_fp8_fp8(a0, b3, acc[0][3], 0, 0, 0);
        acc[1][0] = __builtin_amdgcn_mfma_f32_16x16x32_fp8_fp8(a1, b0, acc[1][0], 0, 0, 0);
        acc[1][1] = __builtin_amdgcn_mfma_f32_16x16x32_fp8_fp8(a1, b1, acc[1][1], 0, 0, 0);
        acc[1][2] = __builtin_amdgcn_mfma_f32_16x16x32_fp8_fp8(a1, b2, acc[1][2], 0, 0, 0);
        acc[1][3] = __builtin_amdgcn_mfma_f32_16x16x32_fp8_fp8(a1, b3, acc[1][3], 0, 0, 0);
      }

      // ---- epilogue: branchless fast pass + ONE deferred vote ----
      // C/D layout: col = lane&15, row = (lane>>4)*4 + reg. If every d2 in
      // this wave's outputs >= 1: non-eq term EXACTLY 0, eq term exactly d2.
      int r0 = q << 2;
      float sn_[4]; int ln_[4];
      #pragma unroll
      for (int j = 0; j < 4; ++j) {
        int n = (wn << 6) + (j << 4) + lc;
        sn_[j] = sqBl[n]; ln_[j] = laBl[n];
      }
      float ps0 = 0.f, ps1 = 0.f, ps2 = 0.f, ps3 = 0.f;
      float mnall = 1e30f;
      #pragma unroll
      for (int i = 0; i < 2; ++i) {
        int mb = (wm << 5) + (i << 4) + r0;
        f32x4 sm4 = *(const f32x4*)&sqAl[mb];
        int4  lm4 = *(const int4*)&laAl[mb];
        #pragma unroll
        for (int j = 0; j < 4; ++j) {
          float d0  = fmaf(-2.f, acc[i][j][0], sm4[0] + sn_[j]);
          float d1  = fmaf(-2.f, acc[i][j][1], sm4[1] + sn_[j]);
          float d2_ = fmaf(-2.f, acc[i][j][2], sm4[2] + sn_[j]);
          float d3  = fmaf(-2.f, acc[i][j][3], sm4[3] + sn_[j]);
          mnall = fminf(mnall, fminf(fminf(d0, d1), fminf(d2_, d3)));
          ps0 += (lm4.x == ln_[j]) ? d0  : 0.f;
          ps1 += (lm4.y == ln_[j]) ? d1  : 0.f;
          ps2 += (lm4.z == ln_[j]) ? d2_ : 0.f;
          ps3 += (lm4.w == ln_[j]) ? d3  : 0.f;
        }
      }
      if (__builtin_expect(__any(mnall < 1.f), 0)) {
        // exact slow path (diagonal-touching waves only); acc still live
        ps0 = ps1 = ps2 = ps3 = 0.f;
        #pragma unroll
        for (int i = 0; i < 2; ++i) {
          int mb = (wm << 5) + (i << 4) + r0;
          f32x4 sm4 = *(const f32x4*)&sqAl[mb];
          int4  lm4 = *(const int4*)&laAl[mb];
          #pragma unroll
          for (int j = 0; j < 4; ++j) {
            float dc, tt;
            dc = fmaxf(fmaf(-2.f, acc[i][j][0], sm4[0] + sn_[j]), 0.f);
            tt = fmaxf(1.f - sqrtf(dc), 0.f);
            ps0 += (lm4.x == ln_[j]) ? dc : tt * tt;
            dc = fmaxf(fmaf(-2.f, acc[i][j][1], sm4[1] + sn_[j]), 0.f);
            tt = fmaxf(1.f - sqrtf(dc), 0.f);
            ps1 += (lm4.y == ln_[j]) ? dc : tt * tt;
            dc = fmaxf(fmaf(-2.f, acc[i][j][2], sm4[2] + sn_[j]), 0.f);
            tt = fmaxf(1.f - sqrtf(dc), 0.f);
            ps2 += (lm4.z == ln_[j]) ? dc : tt * tt;
            dc = fmaxf(fmaf(-2.f, acc[i][j][3], sm4[3] + sn_[j]), 0.f);
            tt = fmaxf(1.f - sqrtf(dc), 0.f);
            ps3 += (lm4.w == ln_[j]) ? dc : tt * tt;
          }
        }
      }
      float w = (bi == bj) ? 1.f : 2.f;                // symmetry weight
      psum_acc += w * ((ps0 + ps1) + (ps2 + ps3));

      if (!hasNext) break;
      bi = bin; bj = bjn; cur ^= 1;
    }
  }

  // ---- block reduction + ONE device-scope atomicAdd ----
  psum_acc *= (1.f / (8192.f * 8192.f * (float)NREP));  // 2^-29, exact
  #pragma unroll
  for (int off = 32; off; off >>= 1) psum_acc += __shfl_down(psum_acc, off);
  if (lane == 0) red[wave] = psum_acc;
  __syncthreads();
  if (tid == 0) {
    float s = 0.f;
    #pragma unroll
    for (int k = 0; k < 8; ++k) s += red[k];
    atomicAdd(out, s);                               // device-scope default
  }
}

extern "C" void kernel_launch(void* const* d_in, const int* in_sizes, int n_in,
                              void* d_out, int out_size, void* d_ws, size_t ws_size,
                              hipStream_t stream) {
  const float* z      = (const float*)d_in[0];
  const int*   labels = (const int*)d_in[1];
  float*       out    = (float*)d_out;
  unsigned char* zb   = (unsigned char*)d_ws;                         // 1 MB
  float* sq           = (float*)((char*)d_ws + (size_t)NROWS * DIMK); // 32 KB

  prep_kernel<<<NROWS / 8, 256, 0, stream>>>(z, zb, sq);
  loss_kernel<<<NPERS, 512, 0, stream>>>(zb, sq, labels, out);
}

// Round 4
// 72.935 us; speedup vs baseline: 2.1063x; 2.1063x over previous
//
#include <hip/hip_runtime.h>
#include <stdint.h>

// ContrastiveLoss: mean over all pairs of (same-label ? d2 : relu(1-dist)^2)
// z: [8192,128] fp32, labels: [8192] int32. Output: 1 fp32 scalar.
//
// R13: XCD-aware tile ownership. R12 slope probe decomposed the 73.3us:
//   41us  workspace poison fill (harness, in timed window, untouchable)
//   ~3us  prep
//   29.5us loss single-shot  = 11.5us warm + ~18us COLD premium
// FETCH_SIZE 4.4MB/8rep -> cold premium is cross-XCD/L3, not HBM: old map
// (block b -> tiles b, b+512...) scatters each panel's consumers over all
// 8 XCDs => every one of 2080 tile-stages (32KB) misses local L2 (~66MB
// cross-XCD at ~3.7TB/s ~= 18us). New map: XCD x (= b&7) owns rows bi==x
// (mod 8); its 64 blocks share A panels in-XCD-L2 and pull <=1MB of B
// panels once per XCD (~9MB total, 7x cut). Decode is int-only -> SALU
// (deletes sqrtf VALU decode). Tail unchanged (max 5 tiles/block).
// Core compute/staging/epilogue byte-identical to verified R9/R11 core.

#define NROWS 8192
#define DIMK  128
#define NB    64                     // 8192 / 128
#define NTILE (NB * (NB + 1) / 2)    // 2080 upper-triangle tiles
#define NPERS 512                    // persistent blocks (2 per CU)

typedef __attribute__((ext_vector_type(4))) float f32x4;

#define AS_GLOBAL __attribute__((address_space(1)))
#define AS_LDS    __attribute__((address_space(3)))

// Convert z -> fp8 e4m3 with granule-swizzled rows: logical k lives in
// granule g = ((k>>3)&3)<<2 | (k>>5), stored at byte ((g^(row&15))<<3)+(k&7).
// Dot-invariant. Also per-row sum of squares of ROUNDED values (diag d2==0).
__global__ __launch_bounds__(256) void prep_kernel(
    const float* __restrict__ z, unsigned char* __restrict__ zb,
    float* __restrict__ sq) {
  int tid = threadIdx.x;
  int row = (blockIdx.x << 3) + (tid >> 5);          // 8 rows per block
  int c32 = tid & 31;                                // 32 lanes per row
  float4 x = ((const float4*)(z + (size_t)row * DIMK))[c32];
  int u = __builtin_amdgcn_cvt_pk_fp8_f32(x.x, x.y, 0, false);
  u     = __builtin_amdgcn_cvt_pk_fp8_f32(x.z, x.w, u, true);
  float r0 = __builtin_amdgcn_cvt_f32_fp8(u, 0);
  float r1 = __builtin_amdgcn_cvt_f32_fp8(u, 1);
  float r2 = __builtin_amdgcn_cvt_f32_fp8(u, 2);
  float r3 = __builtin_amdgcn_cvt_f32_fp8(u, 3);
  float s = (r0 * r0 + r1 * r1) + (r2 * r2 + r3 * r3);
  int k0 = c32 << 2;                                 // logical k of byte 0
  int g  = (((k0 >> 3) & 3) << 2) | (k0 >> 5);       // granule index
  int p  = ((g ^ (row & 15)) << 3) + (k0 & 7);       // 4B-aligned
  *(uint32_t*)(zb + (size_t)row * DIMK + p) = (uint32_t)u;
  #pragma unroll
  for (int off = 16; off; off >>= 1) s += __shfl_down(s, off, 32);
  if (c32 == 0) sq[row] = s;
}

// XCD-local decode: XCD x owns rows r = x, x+8, ..., x+56. Row r has
// (NB - r) tiles. Flattened index n within the owned set -> (bi, bj).
// Integer-only, uniform (blockIdx-derived) -> compiles to SALU.
__device__ __forceinline__ void decode_tile_x(int x, int n, int& bi, int& bj) {
  int rem = n, k = 0, len = NB - x;       // L_k = NB - x - 8k
  while (rem >= len) { rem -= len; ++k; len -= 8; }
  bi = x + (k << 3);
  bj = bi + rem;
}

// Persistent: 512 blocks x 512 thr (8 waves, 4x2). Block b = (x = b&7,
// slot s = b>>3) computes its XCD's tiles n = s, s+64, ... (< 288-8x),
// double-buffered staging. Each tile: A 16KB + B 16KB (linear copy;
// swizzle baked in zb) + 2KB sq/labels. Ends with ONE device-scope
// atomicAdd into out[0] (harness zeroes out each iteration).
__global__ __launch_bounds__(512, 4) void loss_kernel(
    const unsigned char* __restrict__ zb, const float* __restrict__ sq,
    const int* __restrict__ labels, float* __restrict__ out) {
  __shared__ __align__(16) unsigned char buf[2][32768];   // [A 16K | B 16K]
  __shared__ __align__(16) unsigned char sqlab[2][2048];  // [sqA|laA|sqB|laB]
  __shared__ float red[8];

  int tid = threadIdx.x, lane = tid & 63, wave = tid >> 6;
  int wm = wave >> 1, wn = wave & 1;
  int lc = lane & 15;                                // frag row (A)/col (out)
  int q  = lane >> 4;                                // quad: k-granule select

  // sq/label staging role for this wave (one masked DMA per tile):
  //   w0,w1->sqA halves; w2,w3->laA; w4,w5->sqB; w6,w7->laB
  int sl_isB  = wave >> 2;
  int sl_isLa = (wave >> 1) & 1;
  int sl_half = wave & 1;

  float psum_acc = 0.f;

  int x = blockIdx.x & 7;                            // XCD (round-robin)
  int s = blockIdx.x >> 3;                           // slot within XCD
  int tcount = (NB / 2) * (NB + 1) / 4 * 0 + (288 - 8 * x);  // tiles owned
  int n = s;
  if (n < tcount) {                                  // (always true: s<=63<232)
  int bi, bj;
  decode_tile_x(x, n, bi, bj);

  // ---- prologue: stage tile n into buffer 0 ----
  {
    const unsigned char* Ab = zb + (((size_t)bi << 7) * DIMK);
    const unsigned char* Bb = zb + (((size_t)bj << 7) * DIMK);
    #pragma unroll
    for (int it = 0; it < 2; ++it) {
      int L0 = (it << 9) + (wave << 6);
      __builtin_amdgcn_global_load_lds(
          (const AS_GLOBAL void*)(uintptr_t)(Ab + (size_t)(L0 + lane) * 16),
          (AS_LDS void*)(uintptr_t)(&buf[0][(size_t)L0 * 16]), 16, 0, 0);
      __builtin_amdgcn_global_load_lds(
          (const AS_GLOBAL void*)(uintptr_t)(Bb + (size_t)(L0 + lane) * 16),
          (AS_LDS void*)(uintptr_t)(&buf[0][16384 + (size_t)L0 * 16]), 16, 0, 0);
    }
    const char* p0 = sl_isLa ? (const char*)labels : (const char*)sq;
    const char* src = p0 + ((size_t)((sl_isB ? bj : bi) << 7) << 2)
                         + (sl_half << 8);
    if (lane < 16)
      __builtin_amdgcn_global_load_lds(
          (const AS_GLOBAL void*)(uintptr_t)(src + lane * 16),
          (AS_LDS void*)(uintptr_t)(&sqlab[0][wave << 8]), 16, 0, 0);
  }

  int cur = 0;
  for (;; n += 64) {
    int nn = n + 64;
    bool hasNext = nn < tcount;

    // ---- wait for current tile's DMA (issued a full iteration ago) ----
    asm volatile("s_waitcnt vmcnt(0)" ::: "memory");
    __syncthreads();   // implicit drain is free: vmcnt already 0

    // ---- prefetch next tile into the other buffer ----
    int bin = bi, bjn = bj;
    if (hasNext) {
      decode_tile_x(x, nn, bin, bjn);
      int nc = cur ^ 1;
      const unsigned char* Ab = zb + (((size_t)bin << 7) * DIMK);
      const unsigned char* Bb = zb + (((size_t)bjn << 7) * DIMK);
      #pragma unroll
      for (int it = 0; it < 2; ++it) {
        int L0 = (it << 9) + (wave << 6);
        __builtin_amdgcn_global_load_lds(
            (const AS_GLOBAL void*)(uintptr_t)(Ab + (size_t)(L0 + lane) * 16),
            (AS_LDS void*)(uintptr_t)(&buf[nc][(size_t)L0 * 16]), 16, 0, 0);
        __builtin_amdgcn_global_load_lds(
            (const AS_GLOBAL void*)(uintptr_t)(Bb + (size_t)(L0 + lane) * 16),
            (AS_LDS void*)(uintptr_t)(&buf[nc][16384 + (size_t)L0 * 16]), 16, 0, 0);
      }
      const char* p0 = sl_isLa ? (const char*)labels : (const char*)sq;
      const char* src = p0 + ((size_t)((sl_isB ? bjn : bin) << 7) << 2)
                           + (sl_half << 8);
      if (lane < 16)
        __builtin_amdgcn_global_load_lds(
            (const AS_GLOBAL void*)(uintptr_t)(src + lane * 16),
            (AS_LDS void*)(uintptr_t)(&sqlab[nc][wave << 8]), 16, 0, 0);
    }

    // ---- compute tile n from buf[cur] ----
    const unsigned char* ldsA = &buf[cur][0];
    const unsigned char* ldsB = &buf[cur][16384];
    const float* sqAl = (const float*)&sqlab[cur][0];
    const int*   laAl = (const int*)&sqlab[cur][512];
    const float* sqBl = (const float*)&sqlab[cur][1024];
    const int*   laBl = (const int*)&sqlab[cur][1536];

    f32x4 acc[2][4] = {};
    #pragma unroll
    for (int ks = 0; ks < 4; ++ks) {
      int so = ((((q << 2) | ks) ^ lc) << 3);        // swizzled slot offset
      long a0 = *(const long*)(ldsA + ((wm << 5)      + lc) * 128 + so);
      long a1 = *(const long*)(ldsA + ((wm << 5) + 16 + lc) * 128 + so);
      long b0 = *(const long*)(ldsB + ((wn << 6)      + lc) * 128 + so);
      long b1 = *(const long*)(ldsB + ((wn << 6) + 16 + lc) * 128 + so);
      long b2 = *(const long*)(ldsB + ((wn << 6) + 32 + lc) * 128 + so);
      long b3 = *(const long*)(ldsB + ((wn << 6) + 48 + lc) * 128 + so);
      acc[0][0] = __builtin_amdgcn_mfma_f32_16x16x32_fp8_fp8(a0, b0, acc[0][0], 0, 0, 0);
      acc[0][1] = __builtin_amdgcn_mfma_f32_16x16x32_fp8_fp8(a0, b1, acc[0][1], 0, 0, 0);
      acc[0][2] = __builtin_amdgcn_mfma_f32_16x16x32_fp8_fp8(a0, b2, acc[0][2], 0, 0, 0);
      acc[0][3] = __builtin_amdgcn_mfma_f32_16x16x32_fp8_fp8(a0, b3, acc[0][3], 0, 0, 0);
      acc[1][0] = __builtin_amdgcn_mfma_f32_16x16x32_fp8_fp8(a1, b0, acc[1][0], 0, 0, 0);
      acc[1][1] = __builtin_amdgcn_mfma_f32_16x16x32_fp8_fp8(a1, b1, acc[1][1], 0, 0, 0);
      acc[1][2] = __builtin_amdgcn_mfma_f32_16x16x32_fp8_fp8(a1, b2, acc[1][2], 0, 0, 0);
      acc[1][3] = __builtin_amdgcn_mfma_f32_16x16x32_fp8_fp8(a1, b3, acc[1][3], 0, 0, 0);
    }

    // ---- epilogue: branchless fast pass + ONE deferred vote ----
    // C/D layout: col = lane&15, row = (lane>>4)*4 + reg. If every d2 in
    // this wave's outputs >= 1: non-eq term EXACTLY 0, eq term exactly d2.
    int r0 = q << 2;
    float sn_[4]; int ln_[4];
    #pragma unroll
    for (int j = 0; j < 4; ++j) {
      int nidx = (wn << 6) + (j << 4) + lc;
      sn_[j] = sqBl[nidx]; ln_[j] = laBl[nidx];
    }
    float ps0 = 0.f, ps1 = 0.f, ps2 = 0.f, ps3 = 0.f;
    float mnall = 1e30f;
    #pragma unroll
    for (int i = 0; i < 2; ++i) {
      int mb = (wm << 5) + (i << 4) + r0;
      f32x4 sm4 = *(const f32x4*)&sqAl[mb];
      int4  lm4 = *(const int4*)&laAl[mb];
      #pragma unroll
      for (int j = 0; j < 4; ++j) {
        float d0  = fmaf(-2.f, acc[i][j][0], sm4[0] + sn_[j]);
        float d1  = fmaf(-2.f, acc[i][j][1], sm4[1] + sn_[j]);
        float d2_ = fmaf(-2.f, acc[i][j][2], sm4[2] + sn_[j]);
        float d3  = fmaf(-2.f, acc[i][j][3], sm4[3] + sn_[j]);
        mnall = fminf(mnall, fminf(fminf(d0, d1), fminf(d2_, d3)));
        ps0 += (lm4.x == ln_[j]) ? d0  : 0.f;
        ps1 += (lm4.y == ln_[j]) ? d1  : 0.f;
        ps2 += (lm4.z == ln_[j]) ? d2_ : 0.f;
        ps3 += (lm4.w == ln_[j]) ? d3  : 0.f;
      }
    }
    if (__builtin_expect(__any(mnall < 1.f), 0)) {
      // exact slow path (diagonal-touching waves only); acc still live
      ps0 = ps1 = ps2 = ps3 = 0.f;
      #pragma unroll
      for (int i = 0; i < 2; ++i) {
        int mb = (wm << 5) + (i << 4) + r0;
        f32x4 sm4 = *(const f32x4*)&sqAl[mb];
        int4  lm4 = *(const int4*)&laAl[mb];
        #pragma unroll
        for (int j = 0; j < 4; ++j) {
          float dc, tt;
          dc = fmaxf(fmaf(-2.f, acc[i][j][0], sm4[0] + sn_[j]), 0.f);
          tt = fmaxf(1.f - sqrtf(dc), 0.f);
          ps0 += (lm4.x == ln_[j]) ? dc : tt * tt;
          dc = fmaxf(fmaf(-2.f, acc[i][j][1], sm4[1] + sn_[j]), 0.f);
          tt = fmaxf(1.f - sqrtf(dc), 0.f);
          ps1 += (lm4.y == ln_[j]) ? dc : tt * tt;
          dc = fmaxf(fmaf(-2.f, acc[i][j][2], sm4[2] + sn_[j]), 0.f);
          tt = fmaxf(1.f - sqrtf(dc), 0.f);
          ps2 += (lm4.z == ln_[j]) ? dc : tt * tt;
          dc = fmaxf(fmaf(-2.f, acc[i][j][3], sm4[3] + sn_[j]), 0.f);
          tt = fmaxf(1.f - sqrtf(dc), 0.f);
          ps3 += (lm4.w == ln_[j]) ? dc : tt * tt;
        }
      }
    }
    float w = (bi == bj) ? 1.f : 2.f;                // symmetry weight
    psum_acc += w * ((ps0 + ps1) + (ps2 + ps3));

    if (!hasNext) break;
    bi = bin; bj = bjn; cur ^= 1;
  }
  }  // if (n < tcount)

  // ---- block reduction + ONE device-scope atomicAdd ----
  psum_acc *= (1.f / (8192.f * 8192.f));             // 2^-26, exact
  #pragma unroll
  for (int off = 32; off; off >>= 1) psum_acc += __shfl_down(psum_acc, off);
  if (lane == 0) red[wave] = psum_acc;
  __syncthreads();
  if (tid == 0) {
    float sum = 0.f;
    #pragma unroll
    for (int k = 0; k < 8; ++k) sum += red[k];
    atomicAdd(out, sum);                             // device-scope default
  }
}

extern "C" void kernel_launch(void* const* d_in, const int* in_sizes, int n_in,
                              void* d_out, int out_size, void* d_ws, size_t ws_size,
                              hipStream_t stream) {
  const float* z      = (const float*)d_in[0];
  const int*   labels = (const int*)d_in[1];
  float*       out    = (float*)d_out;
  unsigned char* zb   = (unsigned char*)d_ws;                         // 1 MB
  float* sq           = (float*)((char*)d_ws + (size_t)NROWS * DIMK); // 32 KB

  prep_kernel<<<NROWS / 8, 256, 0, stream>>>(z, zb, sq);
  loss_kernel<<<NPERS, 512, 0, stream>>>(zb, sq, labels, out);
}